// Round 5
// baseline (186.873 us; speedup 1.0000x reference)
//
#include <hip/hip_runtime.h>

// Problem: B=8, L=2048, H=256. fp32 in/out.
#define B_ 8
#define L_ 2048
#define H_ 256
#define LOG2E 1.4426950408889634f

typedef _Float16 half8 __attribute__((ext_vector_type(8)));
typedef _Float16 half4_t __attribute__((ext_vector_type(4)));
typedef float f32x4 __attribute__((ext_vector_type(4)));

__device__ __forceinline__ float fast_tanh(float x) {
    const float e2 = __expf(2.f * x);
    return 1.f - 2.f * __builtin_amdgcn_rcpf(e2 + 1.f);
}

// Score in exp2 domain: s2 = (st*m + cm) * LOG2E * base(d).
// MUST be the single shared definition (prepass max vs main-loop scores need
// bit-identical rounding so exp2(s2 - max) <= 1).
__device__ __forceinline__ float score_arg(float st, float cmv, float mv, int d) {
    const float x = fmaf(st, mv, cmv) * LOG2E;
    const float t = (d == 0) ? 0.5f
                             : __builtin_amdgcn_rcpf(__log2f(2.0f + (float)d));
    return x * t;
}

// ---------------------------------------------------------------------------
// prep (unchanged from R4): one block = 64 rows of text (mat=0) or opin (mat=1).
// MFMA GEMM rows@W^T (fp16 in, fp32 acc), W dbuf in LDS, 1 barrier/chunk.
// mat=1 emits V^T fp16 chunk-tiled: vtg[((b*32+chunk)*256+h)*64+jj].
// ---------------------------------------------------------------------------
__global__ __launch_bounds__(256, 2) void prep_kernel(
    const float* __restrict__ opin, const float* __restrict__ text,
    const int* __restrict__ pos_ids,
    const float* __restrict__ Wt, const float* __restrict__ bt,
    const float* __restrict__ Wo, const float* __restrict__ wa,
    const float* __restrict__ ba,
    float* __restrict__ ws_st, float2* __restrict__ ws_cm,
    _Float16* __restrict__ vtg)
{
    __shared__ __align__(16) _Float16 a_lds[4][8][512];
    __shared__ __align__(16) _Float16 w_lds[2][16][512];

    const int tid  = threadIdx.x;
    const int lane = tid & 63;
    const int rg   = tid >> 6;
    const int mat  = blockIdx.x & 1;
    const size_t g0 = (size_t)(blockIdx.x >> 1) * 64;

    const float* __restrict__ src = mat ? opin : text;
    const float* __restrict__ W   = mat ? Wo   : Wt;

#pragma unroll
    for (int v = 0; v < 16; ++v) {
        const int idx = v * 256 + tid;
        const int row = idx >> 6;
        const int k   = (idx & 63) * 4;
        const float4 f = *(const float4*)(src + (g0 + row) * 256 + k);
        half4_t h = { (_Float16)f.x, (_Float16)f.y, (_Float16)f.z, (_Float16)f.w };
        const int off = ((row & 15) + 16 * ((k >> 3) & 3)) * 8 + (k & 7);
        *(half4_t*)&a_lds[row >> 4][k >> 5][off] = h;
    }

    float4 wreg[8];
    const int wn_base = tid >> 3;
    const int wk      = (tid & 7) * 4;
#pragma unroll
    for (int p = 0; p < 8; ++p)
        wreg[p] = *(const float4*)(W + (p * 32 + wn_base) * 256 + wk);

    __syncthreads();

    f32x4 acc[16];
#pragma unroll
    for (int nt = 0; nt < 16; ++nt) acc[nt] = (f32x4){0.f, 0.f, 0.f, 0.f};

    for (int kc = 0; kc < 8; ++kc) {
#pragma unroll
        for (int p = 0; p < 8; ++p) {
            const int n = p * 32 + wn_base;
            half4_t h = { (_Float16)wreg[p].x, (_Float16)wreg[p].y,
                          (_Float16)wreg[p].z, (_Float16)wreg[p].w };
            const int off = ((n & 15) + 16 * (wk >> 3)) * 8 + (wk & 7);
            *(half4_t*)&w_lds[kc & 1][n >> 4][off] = h;
        }
        __syncthreads();
        if (kc + 1 < 8) {
#pragma unroll
            for (int p = 0; p < 8; ++p)
                wreg[p] = *(const float4*)(W + (p * 32 + wn_base) * 256 + (kc + 1) * 32 + wk);
        }
        const half8 afrag = *(const half8*)&a_lds[rg][kc][lane * 8];
#pragma unroll
        for (int nt = 0; nt < 16; ++nt) {
            const half8 bfrag = *(const half8*)&w_lds[kc & 1][nt][lane * 8];
            acc[nt] = __builtin_amdgcn_mfma_f32_16x16x32_f16(afrag, bfrag, acc[nt], 0, 0, 0);
        }
    }

    const int em = lane & 15, q = lane >> 4;
    float rowsum[4] = {0.f, 0.f, 0.f, 0.f};
#pragma unroll
    for (int nt = 0; nt < 16; ++nt) {
        const int col  = nt * 16 + em;
        const float btv = mat ? 0.f : bt[col];
        const float wav = wa[mat * 256 + col];
#pragma unroll
        for (int r = 0; r < 4; ++r)
            rowsum[r] += fast_tanh(acc[nt][r] + btv) * wav;
    }
#pragma unroll
    for (int r = 0; r < 4; ++r) {
        float s = rowsum[r];
        s += __shfl_xor(s, 1, 64);
        s += __shfl_xor(s, 2, 64);
        s += __shfl_xor(s, 4, 64);
        s += __shfl_xor(s, 8, 64);
        if (em == 0) {
            const size_t grow = g0 + rg * 16 + q * 4 + r;
            if (mat == 0) {
                ws_st[grow] = s;
            } else {
                const int p = pos_ids[grow];
                const bool isop = (p==19)|(p==20)|(p==21)|(p==33)|(p==34)|(p==35)|((p>=41)&(p<=46));
                const float mult = isop ? 8.f : 1.f;
                ws_cm[grow] = make_float2((s + ba[0]) * mult, mult);
            }
        }
    }

    if (mat == 1) {
        const int h = tid;
        const size_t b = g0 >> 11;
        const int chunk = (int)((g0 & 2047) >> 6);
        const int kcS = h >> 5, kq = (h >> 3) & 3, jh = h & 7;
        _Float16 vals[64];
#pragma unroll
        for (int r = 0; r < 64; ++r)
            vals[r] = a_lds[r >> 4][kcS][((r & 15) + 16 * kq) * 8 + jh];
        _Float16* dst = vtg + ((b * 32 + chunk) * 256 + h) * 64;
#pragma unroll
        for (int w = 0; w < 8; ++w)
            *(half8*)(dst + w * 8) = *(half8*)&vals[w * 8];
    }
}

// ---------------------------------------------------------------------------
// attn: 256 blocks = (b, 64-row tile), 512 threads = 8 waves (rowg, hh).
// Duplication-free scores: wave (rowg, hh) computes P-frag (rowg, rt=hh>>1,
// ks=hh&1) directly in MFMA A-layout (8 exp2/lane/chunk), exchanged via
// dbuf p_lds. MFMA tile per wave: rows rowg*32..+31 (rt=2), cols hh*64..+63
// (ht=4), B-frags reused across rt. V^T dbuf vt2[jb][h][8] (2-way = free).
// ONE barrier per chunk. cm from L2; base(d) via v_log+v_rcp (no LDS table).
// ---------------------------------------------------------------------------
__global__ __launch_bounds__(512, 2) void attn_kernel(
    const float* __restrict__ ws_st, const float2* __restrict__ ws_cm,
    const _Float16* __restrict__ vtg, float* __restrict__ out)
{
    __shared__ __align__(16) _Float16 vt2[2][8][256][8];       // 64 KB dbuf
    __shared__ __align__(16) _Float16 p_lds[2][2][2][2][512];  // 16 KB dbuf
    __shared__ float m_tbl[64];
    __shared__ float zpart[2][2][2][16];

    const int tid  = threadIdx.x;
    const int lane = tid & 63;
    const int wid  = tid >> 6;
    const int rowg = wid & 1;
    const int hh   = wid >> 1;        // 0..3
    const int rt_w = hh >> 1;         // score-ownership: rt quarter
    const int ks_w = hh & 1;          // score-ownership: ks half
    const int em   = lane & 15;
    const int quad = lane >> 4;
    const int b    = blockIdx.x & 7;
    const int i0   = (blockIdx.x >> 3) * 64;

    const _Float16* vsrc_base = vtg + (size_t)(b * 32) * (256 * 64);

    // staging: thread handles 4 16B-elems g = wid*256 + i*64 + lane
    int srcoff[4];
#pragma unroll
    for (int i = 0; i < 4; ++i) {
        const int g  = wid * 256 + i * 64 + lane;
        const int h  = g & 255;
        const int jb = g >> 8;
        srcoff[i] = h * 64 + jb * 8;
    }

    // prefetch V^T chunk 0 (lands during prepass)
    half8 vr[4];
#pragma unroll
    for (int i = 0; i < 4; ++i)
        vr[i] = *(const half8*)(vsrc_base + srcoff[i]);

    // ---- exact row-max prepass: wave -> 8 rows, 8 lanes per row ----
    {
        const int prow = wid * 8 + (lane >> 3);
        const int gi_p = i0 + prow;
        const float st_p = ws_st[b * 2048 + gi_p];
        const int jg = (lane & 7) * 8;
        float mx = -3.0e38f;
        for (int t = 0; t < 32; ++t) {
            const int j = t * 64 + jg;
            const float4* cmp = (const float4*)(ws_cm + (size_t)b * 2048 + j);
            const float4 c01 = cmp[0], c23 = cmp[1], c45 = cmp[2], c67 = cmp[3];
            const float cmm[8] = {c01.x, c01.z, c23.x, c23.z, c45.x, c45.z, c67.x, c67.z};
            const float mm[8]  = {c01.y, c01.w, c23.y, c23.w, c45.y, c45.w, c67.y, c67.w};
#pragma unroll
            for (int e = 0; e < 8; ++e) {
                int d = gi_p - (j + e); d = d < 0 ? -d : d;
                mx = fmaxf(mx, score_arg(st_p, cmm[e], mm[e], d));
            }
        }
        mx = fmaxf(mx, __shfl_xor(mx, 1, 64));
        mx = fmaxf(mx, __shfl_xor(mx, 2, 64));
        mx = fmaxf(mx, __shfl_xor(mx, 4, 64));
        if ((lane & 7) == 0) m_tbl[prow] = mx;
    }
    __syncthreads();   // m_tbl ready

    // per-lane score-row constants
    const int myrow = rowg * 32 + rt_w * 16 + em;
    const int gi    = i0 + myrow;
    const float st_r = ws_st[b * 2048 + gi];
    const float mp   = m_tbl[myrow];
    const int  joff  = ks_w * 32 + quad * 8;

    f32x4 acc[2][4];
#pragma unroll
    for (int rt = 0; rt < 2; ++rt)
#pragma unroll
        for (int ht = 0; ht < 4; ++ht) acc[rt][ht] = (f32x4){0.f, 0.f, 0.f, 0.f};
    float zacc = 0.f;

    // ---- main K loop: ONE barrier per chunk (everything double-buffered) ----
    for (int kc = 0; kc < 32; ++kc) {
        const int buf = kc & 1;
        // stage V^T writes (prefetched regs)
        {
            _Float16* vb = (_Float16*)vt2[buf];
#pragma unroll
            for (int i = 0; i < 4; ++i)
                *(half8*)(vb + (wid * 256 + i * 64 + lane) * 8) = vr[i];
        }
        // scores -> own A-frag eighth
        {
            const int j0 = kc * 64;
            const float4* cmp = (const float4*)(ws_cm + (size_t)b * 2048 + j0 + joff);
            const float4 c01 = cmp[0], c23 = cmp[1], c45 = cmp[2], c67 = cmp[3];
            const float cmm[8] = {c01.x, c01.z, c23.x, c23.z, c45.x, c45.z, c67.x, c67.z};
            const float mm[8]  = {c01.y, c01.w, c23.y, c23.w, c45.y, c45.w, c67.y, c67.w};
            const int c0 = gi - (j0 + joff);
            half8 pv;
#pragma unroll
            for (int e = 0; e < 8; ++e) {
                int d = c0 - e; d = d < 0 ? -d : d;
                const float p = __builtin_exp2f(score_arg(st_r, cmm[e], mm[e], d) - mp);
                zacc += p;
                pv[e] = (_Float16)p;
            }
            *(half8*)&p_lds[buf][rowg][rt_w][ks_w][lane * 8] = pv;
        }
        __syncthreads();   // the only barrier: vt2[buf] + p_lds[buf] complete

        // prefetch next chunk (in flight during MFMA)
        if (kc + 1 < 32) {
            const _Float16* vs = vsrc_base + (size_t)(kc + 1) * (256 * 64);
#pragma unroll
            for (int i = 0; i < 4; ++i)
                vr[i] = *(const half8*)(vs + srcoff[i]);
        }

        // MFMA: rt2 x ht4 x ks2, B-frags reused across rt
        {
            half8 af[2][2];
#pragma unroll
            for (int rt = 0; rt < 2; ++rt)
#pragma unroll
                for (int ks = 0; ks < 2; ++ks)
                    af[rt][ks] = *(const half8*)&p_lds[buf][rowg][rt][ks][lane * 8];
#pragma unroll
            for (int ks = 0; ks < 2; ++ks) {
#pragma unroll
                for (int ht = 0; ht < 4; ++ht) {
                    const int hcol = hh * 64 + ht * 16 + em;
                    const half8 bf = *(const half8*)&vt2[buf][ks * 4 + quad][hcol][0];
                    acc[0][ht] = __builtin_amdgcn_mfma_f32_16x16x32_f16(af[0][ks], bf, acc[0][ht], 0, 0, 0);
                    acc[1][ht] = __builtin_amdgcn_mfma_f32_16x16x32_f16(af[1][ks], bf, acc[1][ht], 0, 0, 0);
                }
            }
        }
    }

    // ---- Z: quad-reduce, cross-wave via zpart ----
    zacc += __shfl_xor(zacc, 16, 64);
    zacc += __shfl_xor(zacc, 32, 64);
    if (quad == 0) zpart[rowg][rt_w][ks_w][em] = zacc;
    __syncthreads();

    // ---- epilogue: C/D row = quad*4+reg, col = em ----
#pragma unroll
    for (int rt = 0; rt < 2; ++rt) {
#pragma unroll
        for (int r = 0; r < 4; ++r) {
            const int rloc = quad * 4 + r;
            const int row  = rowg * 32 + rt * 16 + rloc;
            const float rz = 1.0f / (zpart[rowg][rt][0][rloc] + zpart[rowg][rt][1][rloc]);
            float* op = out + ((size_t)b * 2048 + (i0 + row)) * 256 + hh * 64 + em;
#pragma unroll
            for (int ht = 0; ht < 4; ++ht)
                op[ht * 16] = acc[rt][ht][r] * rz;
        }
    }
}

// ---------------------------------------------------------------------------
extern "C" void kernel_launch(void* const* d_in, const int* in_sizes, int n_in,
                              void* d_out, int out_size, void* d_ws, size_t ws_size,
                              hipStream_t stream) {
    const float* opin  = (const float*)d_in[0];
    const float* text  = (const float*)d_in[1];
    const int* pos_ids = (const int*)d_in[2];
    const float* Wt    = (const float*)d_in[3];
    const float* bt    = (const float*)d_in[4];
    const float* Wo    = (const float*)d_in[5];
    const float* wa    = (const float*)d_in[6];
    const float* ba    = (const float*)d_in[7];
    float* out         = (float*)d_out;

    // workspace: st (64 KB) | cm (128 KB) | vtg fp16 chunk-tiled (8 MB)
    float*  ws_st = (float*)d_ws;
    float2* ws_cm = (float2*)((char*)d_ws + 65536);
    _Float16* vtg = (_Float16*)((char*)d_ws + 65536 + 131072);

    prep_kernel<<<512, 256, 0, stream>>>(opin, text, pos_ids, Wt, bt, Wo, wa, ba,
                                         ws_st, ws_cm, vtg);
    attn_kernel<<<256, 512, 0, stream>>>(ws_st, ws_cm, vtg, out);
}